// Round 3
// baseline (158.461 us; speedup 1.0000x reference)
//
#include <hip/hip_runtime.h>
#include <hip/hip_cooperative_groups.h>

namespace cg = cooperative_groups;

#define NUM_LAYERS 32
#define HIDDEN 2048
#define RANK 64
#define BATCH 2048
#define KC 128               // h-chunk (K) per proj chunk
#define HCH 128              // h-chunk (N) per delta chunk
#define MB_P 64              // samples per pass, proj phase
#define MB_D 128             // samples per pass, delta phase
#define ZPAD 136             // ushort row stride, z tile (16B-aligned, 4-bank shift)
#define VPAD 136             // ushort row stride, v tile
#define UPAD 72              // ushort row stride, u tile
#define PPAD 72              // ushort row stride, p tile

typedef __attribute__((ext_vector_type(8))) short bf16x8;
typedef __attribute__((ext_vector_type(4))) float f32x4;

static __device__ __forceinline__ ushort f2bf(float x) {
    unsigned b = __builtin_bit_cast(unsigned, x);
    b += 0x7fffu + ((b >> 16) & 1u);          // round-to-nearest-even
    return (ushort)(b >> 16);
}
static __device__ __forceinline__ ushort4 pack4(float4 v) {
    ushort4 r; r.x = f2bf(v.x); r.y = f2bf(v.y); r.z = f2bf(v.z); r.w = f2bf(v.w);
    return r;
}

// Fused: phase A (proj += Z·V over 2 k-chunks) -> grid sync -> phase B
// (out = z + P·U^T over 2 h-chunks). 256 blocks x 512 thr, 1 block/CU.
// Block owns layer l=bid>>3, chunk-pair {part, part+8}. Compaction done ONCE.
// All proj-independent phase-B loads issued before the grid sync.
__global__ __launch_bounds__(512)
void k_fused(const float* __restrict__ z, const float* __restrict__ vm,
             const float* __restrict__ um, const int* __restrict__ ids,
             float* __restrict__ proj, float* __restrict__ out)
{
    const int bid = blockIdx.x;
    const int l = bid >> 3, part = bid & 7;
    const int t = threadIdx.x;
    const int w = t >> 6, lane = t & 63;
    const int m16 = lane & 15, quad = lane >> 4;

    __shared__ int lidx[BATCH];              // 8 KB
    __shared__ int nsh;
    __shared__ __align__(16) char smem[55296];   // phase-aliased tiles
    ushort* const vt  = (ushort*)smem;               // A: [r][h]  17408 B
    ushort* const zt0 = (ushort*)(smem + 17408);     // A: [si][h] 17408 B
    ushort* const zt1 = (ushort*)(smem + 34816);
    ushort* const ut  = (ushort*)smem;               // B: [h][r]  18432 B
    ushort* const pt0 = (ushort*)(smem + 18432);     // B: [si][r] 18432 B
    ushort* const pt1 = (ushort*)(smem + 36864);

    if (t == 0) nsh = 0;

    // chunk-0 V loads fly over the ids compaction
    float4 vreg[4];
    #pragma unroll
    for (int it = 0; it < 4; ++it) {
        const int idx = it * 512 + t, hh = idx >> 4, rq = idx & 15;
        vreg[it] = *(const float4*)&vm[((size_t)l * HIDDEN + part * KC + hh) * RANK + rq * 4];
    }
    __syncthreads();                         // nsh = 0 visible
    {
        const int4 iv = ((const int4*)ids)[t];   // 512 int4 = all 2048 ids
        if (iv.x == l) lidx[atomicAdd(&nsh, 1)] = t * 4 + 0;
        if (iv.y == l) lidx[atomicAdd(&nsh, 1)] = t * 4 + 1;
        if (iv.z == l) lidx[atomicAdd(&nsh, 1)] = t * 4 + 2;
        if (iv.w == l) lidx[atomicAdd(&nsh, 1)] = t * 4 + 3;
    }
    __syncthreads();                         // lidx, nsh final
    const int n = nsh;

    // ---------------- phase A: proj += Z·V ----------------
    if (n > 0) {
        const int wr = w & 3, wm = w >> 2;
        const int P = (n + MB_P - 1) / MB_P;
        #pragma unroll
        for (int c = 0; c < 2; ++c) {
            const int kbase = (part + c * 8) * KC;
            // pass-0 z gathers: issued before the chunk barrier / vt convert
            float4 zreg[4];
            {
                const int nb = (n < MB_P) ? n : MB_P;
                #pragma unroll
                for (int it = 0; it < 4; ++it) {
                    const int idx = it * 512 + t, si = idx >> 5, q = idx & 31;
                    zreg[it] = make_float4(0.f, 0.f, 0.f, 0.f);
                    if (si < nb)
                        zreg[it] = *(const float4*)&z[(size_t)lidx[si] * HIDDEN + kbase + q * 4];
                }
            }
            if (c == 1) __syncthreads();     // chunk-0 LDS reads complete
            #pragma unroll
            for (int it = 0; it < 4; ++it) { // convert V tile (transposed)
                const int idx = it * 512 + t, hh = idx >> 4, rq = idx & 15;
                vt[(rq * 4 + 0) * VPAD + hh] = f2bf(vreg[it].x);
                vt[(rq * 4 + 1) * VPAD + hh] = f2bf(vreg[it].y);
                vt[(rq * 4 + 2) * VPAD + hh] = f2bf(vreg[it].z);
                vt[(rq * 4 + 3) * VPAD + hh] = f2bf(vreg[it].w);
            }
            if (c == 0) {                    // chunk-1 V loads hide under passes
                #pragma unroll
                for (int it = 0; it < 4; ++it) {
                    const int idx = it * 512 + t, hh = idx >> 4, rq = idx & 15;
                    vreg[it] = *(const float4*)&vm[((size_t)l * HIDDEN + (part + 8) * KC + hh) * RANK + rq * 4];
                }
            }
            for (int p = 0; p < P; ++p) {
                ushort* const ztp = (p & 1) ? zt1 : zt0;
                const int nbr = n - p * MB_P;
                const int nb = (nbr < MB_P) ? nbr : MB_P;
                #pragma unroll
                for (int it = 0; it < 4; ++it) {
                    const int idx = it * 512 + t, si = idx >> 5, q = idx & 31;
                    *(ushort4*)&ztp[si * ZPAD + q * 4] = pack4(zreg[it]);
                }
                __syncthreads();             // vt + ztp visible
                if (p + 1 < P) {             // prefetch next pass
                    const int b2 = (p + 1) * MB_P;
                    const int nb2 = (n - b2 < MB_P) ? (n - b2) : MB_P;
                    #pragma unroll
                    for (int it = 0; it < 4; ++it) {
                        const int idx = it * 512 + t, si = idx >> 5, q = idx & 31;
                        zreg[it] = make_float4(0.f, 0.f, 0.f, 0.f);
                        if (si < nb2)
                            zreg[it] = *(const float4*)&z[(size_t)lidx[b2 + si] * HIDDEN + kbase + q * 4];
                    }
                }
                f32x4 acc0 = {0.f, 0.f, 0.f, 0.f}, acc1 = {0.f, 0.f, 0.f, 0.f};
                const ushort* zr0 = &ztp[(wm * 32 + m16) * ZPAD];
                const ushort* zr1 = zr0 + 16 * ZPAD;
                const ushort* vr  = &vt[(wr * 16 + m16) * VPAD];
                #pragma unroll
                for (int kt = 0; kt < 4; ++kt) {
                    const int koff = kt * 32 + quad * 8;
                    const bf16x8 bf = *(const bf16x8*)&vr[koff];
                    const bf16x8 a0 = *(const bf16x8*)&zr0[koff];
                    const bf16x8 a1 = *(const bf16x8*)&zr1[koff];
                    acc0 = __builtin_amdgcn_mfma_f32_16x16x32_bf16(a0, bf, acc0, 0, 0, 0);
                    acc1 = __builtin_amdgcn_mfma_f32_16x16x32_bf16(a1, bf, acc1, 0, 0, 0);
                }
                // C/D: col(=r)=lane&15, row(=si)=quad*4+reg ; fire-and-forget
                const int r = wr * 16 + m16;
                const int base = p * MB_P;
                #pragma unroll
                for (int reg = 0; reg < 4; ++reg) {
                    const int row = wm * 32 + quad * 4 + reg;
                    if (row < nb)
                        atomicAdd(&proj[(size_t)lidx[base + row] * RANK + r], acc0[reg]);
                    if (row + 16 < nb)
                        atomicAdd(&proj[(size_t)lidx[base + row + 16] * RANK + r], acc1[reg]);
                }
            }
        }
    }

    // ---- issue ALL proj-independent phase-B loads, then grid sync ----
    const int wrB = w & 1, wmB = w >> 1;
    float4 uregA[4], uregB[4];
    float  zep[2][4][4];
    if (n > 0) {
        #pragma unroll
        for (int it = 0; it < 4; ++it) {
            const int idx = it * 512 + t, hh = idx >> 4, rq = idx & 15;
            uregA[it] = *(const float4*)&um[((size_t)l * HIDDEN + part * HCH + hh) * RANK + rq * 4];
            uregB[it] = *(const float4*)&um[((size_t)l * HIDDEN + (part + 8) * HCH + hh) * RANK + rq * 4];
        }
        const int nb = (n < MB_D) ? n : MB_D;
        #pragma unroll
        for (int mt = 0; mt < 2; ++mt)
            #pragma unroll
            for (int reg = 0; reg < 4; ++reg) {
                const int si = wmB * 32 + mt * 16 + quad * 4 + reg;
                const size_t rowb = (si < nb) ? ((size_t)lidx[si] * HIDDEN + part * HCH) : 0;
                #pragma unroll
                for (int nt = 0; nt < 4; ++nt) {
                    const int h = (wrB * 4 + nt) * 16 + m16;
                    zep[mt][nt][reg] = (si < nb) ? z[rowb + h] : 0.f;
                }
            }
    }
    cg::this_grid().sync();                  // proj complete everywhere

    // ---------------- phase B: out = z + P·U^T ----------------
    if (n > 0) {
        const int P = (n + MB_D - 1) / MB_D;
        #pragma unroll
        for (int c = 0; c < 2; ++c) {
            const int hbase = (part + c * 8) * HCH;
            // pass-0 proj loads: first VMEM after the barrier
            float4 preg[4];
            {
                const int nb = (n < MB_D) ? n : MB_D;
                #pragma unroll
                for (int it = 0; it < 4; ++it) {
                    const int idx = it * 512 + t, si = idx >> 4, rq = idx & 15;
                    preg[it] = make_float4(0.f, 0.f, 0.f, 0.f);
                    if (si < nb)
                        preg[it] = *(const float4*)&proj[(size_t)lidx[si] * RANK + rq * 4];
                }
            }
            if (c == 1) {                    // reload z-epilogue for hc1 (pre-sync)
                const int nb = (n < MB_D) ? n : MB_D;
                #pragma unroll
                for (int mt = 0; mt < 2; ++mt)
                    #pragma unroll
                    for (int reg = 0; reg < 4; ++reg) {
                        const int si = wmB * 32 + mt * 16 + quad * 4 + reg;
                        const size_t rowb = (si < nb) ? ((size_t)lidx[si] * HIDDEN + hbase) : 0;
                        #pragma unroll
                        for (int nt = 0; nt < 4; ++nt) {
                            const int h = (wrB * 4 + nt) * 16 + m16;
                            zep[mt][nt][reg] = (si < nb) ? z[rowb + h] : 0.f;
                        }
                    }
                __syncthreads();             // chunk-0 ut/pt reads complete
            }
            #pragma unroll
            for (int it = 0; it < 4; ++it) { // convert U tile
                const int idx = it * 512 + t, hh = idx >> 4, rq = idx & 15;
                const float4 uv = (c == 0) ? uregA[it] : uregB[it];
                *(ushort4*)&ut[hh * UPAD + rq * 4] = pack4(uv);
            }
            for (int p = 0; p < P; ++p) {
                ushort* const ptp = (p & 1) ? pt1 : pt0;
                const int nbr = n - p * MB_D;
                const int nb = (nbr < MB_D) ? nbr : MB_D;
                const int base = p * MB_D;
                #pragma unroll
                for (int it = 0; it < 4; ++it) {
                    const int idx = it * 512 + t, si = idx >> 4, rq = idx & 15;
                    *(ushort4*)&ptp[si * PPAD + rq * 4] = pack4(preg[it]);
                }
                __syncthreads();             // ut + ptp visible

                f32x4 acc[2][4];
                #pragma unroll
                for (int mt = 0; mt < 2; ++mt)
                    #pragma unroll
                    for (int nt = 0; nt < 4; ++nt)
                        acc[mt][nt] = (f32x4){0.f, 0.f, 0.f, 0.f};

                const ushort* pr0 = &ptp[(wmB * 32 + m16) * PPAD];
                const ushort* pr1 = pr0 + 16 * PPAD;
                #pragma unroll
                for (int kt = 0; kt < 2; ++kt) {
                    const int koff = kt * 32 + quad * 8;
                    const bf16x8 a0 = *(const bf16x8*)&pr0[koff];
                    const bf16x8 a1 = *(const bf16x8*)&pr1[koff];
                    #pragma unroll
                    for (int nt = 0; nt < 4; ++nt) {
                        const int h = (wrB * 4 + nt) * 16 + m16;
                        const bf16x8 bf = *(const bf16x8*)&ut[h * UPAD + koff];
                        acc[0][nt] = __builtin_amdgcn_mfma_f32_16x16x32_bf16(a0, bf, acc[0][nt], 0, 0, 0);
                        acc[1][nt] = __builtin_amdgcn_mfma_f32_16x16x32_bf16(a1, bf, acc[1][nt], 0, 0, 0);
                    }
                }
                // epilogue: out = z + delta (z prefetched ahead)
                #pragma unroll
                for (int mt = 0; mt < 2; ++mt)
                    #pragma unroll
                    for (int reg = 0; reg < 4; ++reg) {
                        const int si = wmB * 32 + mt * 16 + quad * 4 + reg;
                        if (si < nb) {
                            const size_t rowb = (size_t)lidx[base + si] * HIDDEN + hbase;
                            #pragma unroll
                            for (int nt = 0; nt < 4; ++nt) {
                                const int h = (wrB * 4 + nt) * 16 + m16;
                                out[rowb + h] = zep[mt][nt][reg] + acc[mt][nt][reg];
                            }
                        }
                    }
                if (p + 1 < P) {             // rare: n > 128
                    const int b2 = (p + 1) * MB_D;
                    const int nb2 = (n - b2 < MB_D) ? (n - b2) : MB_D;
                    #pragma unroll
                    for (int it = 0; it < 4; ++it) {
                        const int idx = it * 512 + t, si = idx >> 4, rq = idx & 15;
                        preg[it] = make_float4(0.f, 0.f, 0.f, 0.f);
                        if (si < nb2)
                            preg[it] = *(const float4*)&proj[(size_t)lidx[b2 + si] * RANK + rq * 4];
                    }
                    #pragma unroll
                    for (int mt = 0; mt < 2; ++mt)
                        #pragma unroll
                        for (int reg = 0; reg < 4; ++reg) {
                            const int si = wmB * 32 + mt * 16 + quad * 4 + reg;
                            const size_t rowb = (si < nb2) ? ((size_t)lidx[b2 + si] * HIDDEN + hbase) : 0;
                            #pragma unroll
                            for (int nt = 0; nt < 4; ++nt) {
                                const int h = (wrB * 4 + nt) * 16 + m16;
                                zep[mt][nt][reg] = (si < nb2) ? z[rowb + h] : 0.f;
                            }
                        }
                }
            }
        }
    }
}

// ---------- fallback pair (round-2, known-good) if coop launch rejected ----------
__global__ __launch_bounds__(512)
void k_proj_fb(const float* __restrict__ z, const float* __restrict__ v,
               const int* __restrict__ ids, float* __restrict__ proj)
{
    const int kc = blockIdx.x, l = blockIdx.y;
    const int t = threadIdx.x;
    const int w = t >> 6, lane = t & 63;
    const int m16 = lane & 15, quad = lane >> 4;
    const int wr = w & 3, wm = w >> 2;
    const int kbase = kc * KC;

    __shared__ int    lidx[BATCH];
    __shared__ int    nsh;
    __shared__ ushort vt[RANK * VPAD];
    __shared__ ushort zt[2][MB_P * ZPAD];

    if (t == 0) nsh = 0;
    float4 vreg[4];
    #pragma unroll
    for (int it = 0; it < 4; ++it) {
        const int idx = it * 512 + t, hh = idx >> 4, rq = idx & 15;
        vreg[it] = *(const float4*)&v[((size_t)l * HIDDEN + kbase + hh) * RANK + rq * 4];
    }
    __syncthreads();
    {
        const int4 iv = ((const int4*)ids)[t];
        if (iv.x == l) lidx[atomicAdd(&nsh, 1)] = t * 4 + 0;
        if (iv.y == l) lidx[atomicAdd(&nsh, 1)] = t * 4 + 1;
        if (iv.z == l) lidx[atomicAdd(&nsh, 1)] = t * 4 + 2;
        if (iv.w == l) lidx[atomicAdd(&nsh, 1)] = t * 4 + 3;
    }
    __syncthreads();
    const int n = nsh;
    if (n == 0) return;

    const int P = (n + MB_P - 1) / MB_P;
    float4 zreg[4];
    {
        const int nb = (n < MB_P) ? n : MB_P;
        #pragma unroll
        for (int it = 0; it < 4; ++it) {
            const int idx = it * 512 + t, si = idx >> 5, q = idx & 31;
            zreg[it] = make_float4(0.f, 0.f, 0.f, 0.f);
            if (si < nb)
                zreg[it] = *(const float4*)&z[(size_t)lidx[si] * HIDDEN + kbase + q * 4];
        }
    }
    #pragma unroll
    for (int it = 0; it < 4; ++it) {
        const int idx = it * 512 + t, hh = idx >> 4, rq = idx & 15;
        vt[(rq * 4 + 0) * VPAD + hh] = f2bf(vreg[it].x);
        vt[(rq * 4 + 1) * VPAD + hh] = f2bf(vreg[it].y);
        vt[(rq * 4 + 2) * VPAD + hh] = f2bf(vreg[it].z);
        vt[(rq * 4 + 3) * VPAD + hh] = f2bf(vreg[it].w);
    }
    for (int p = 0; p < P; ++p) {
        const int nbr = n - p * MB_P;
        const int nb = (nbr < MB_P) ? nbr : MB_P;
        #pragma unroll
        for (int it = 0; it < 4; ++it) {
            const int idx = it * 512 + t, si = idx >> 5, q = idx & 31;
            *(ushort4*)&zt[p & 1][si * ZPAD + q * 4] = pack4(zreg[it]);
        }
        __syncthreads();
        if (p + 1 < P) {
            const int b2 = (p + 1) * MB_P;
            const int nb2 = (n - b2 < MB_P) ? (n - b2) : MB_P;
            #pragma unroll
            for (int it = 0; it < 4; ++it) {
                const int idx = it * 512 + t, si = idx >> 5, q = idx & 31;
                zreg[it] = make_float4(0.f, 0.f, 0.f, 0.f);
                if (si < nb2)
                    zreg[it] = *(const float4*)&z[(size_t)lidx[b2 + si] * HIDDEN + kbase + q * 4];
            }
        }
        f32x4 acc0 = {0.f, 0.f, 0.f, 0.f}, acc1 = {0.f, 0.f, 0.f, 0.f};
        const ushort* zr0 = &zt[p & 1][(wm * 32 + m16) * ZPAD];
        const ushort* zr1 = zr0 + 16 * ZPAD;
        const ushort* vr  = &vt[(wr * 16 + m16) * VPAD];
        #pragma unroll
        for (int kt = 0; kt < 4; ++kt) {
            const int koff = kt * 32 + quad * 8;
            const bf16x8 bf = *(const bf16x8*)&vr[koff];
            const bf16x8 a0 = *(const bf16x8*)&zr0[koff];
            const bf16x8 a1 = *(const bf16x8*)&zr1[koff];
            acc0 = __builtin_amdgcn_mfma_f32_16x16x32_bf16(a0, bf, acc0, 0, 0, 0);
            acc1 = __builtin_amdgcn_mfma_f32_16x16x32_bf16(a1, bf, acc1, 0, 0, 0);
        }
        const int r = wr * 16 + m16;
        const int base = p * MB_P;
        #pragma unroll
        for (int reg = 0; reg < 4; ++reg) {
            const int row = wm * 32 + quad * 4 + reg;
            if (row < nb)
                atomicAdd(&proj[(size_t)lidx[base + row] * RANK + r], acc0[reg]);
            if (row + 16 < nb)
                atomicAdd(&proj[(size_t)lidx[base + row + 16] * RANK + r], acc1[reg]);
        }
    }
}

__global__ __launch_bounds__(512)
void k_delta_fb(const float* __restrict__ z, const float* __restrict__ u,
                const int* __restrict__ ids, const float* __restrict__ proj,
                float* __restrict__ out)
{
    const int hc = blockIdx.x, l = blockIdx.y;
    const int t = threadIdx.x;
    const int w = t >> 6, lane = t & 63;
    const int m16 = lane & 15, quad = lane >> 4;
    const int wr = w & 1, wm = w >> 1;
    const int hbase = hc * HCH;

    __shared__ int    lidx[BATCH];
    __shared__ int    nsh;
    __shared__ ushort ut[HCH * UPAD];
    __shared__ ushort pt[2][MB_D * PPAD];

    if (t == 0) nsh = 0;
    float4 ureg[4];
    #pragma unroll
    for (int it = 0; it < 4; ++it) {
        const int idx = it * 512 + t, hh = idx >> 4, rq = idx & 15;
        ureg[it] = *(const float4*)&u[((size_t)l * HIDDEN + hbase + hh) * RANK + rq * 4];
    }
    __syncthreads();
    {
        const int4 iv = ((const int4*)ids)[t];
        if (iv.x == l) lidx[atomicAdd(&nsh, 1)] = t * 4 + 0;
        if (iv.y == l) lidx[atomicAdd(&nsh, 1)] = t * 4 + 1;
        if (iv.z == l) lidx[atomicAdd(&nsh, 1)] = t * 4 + 2;
        if (iv.w == l) lidx[atomicAdd(&nsh, 1)] = t * 4 + 3;
    }
    __syncthreads();
    const int n = nsh;
    if (n == 0) return;

    const int P = (n + MB_D - 1) / MB_D;
    float4 preg[4];
    float  zep[2][4][4];
    {
        const int nb = (n < MB_D) ? n : MB_D;
        #pragma unroll
        for (int it = 0; it < 4; ++it) {
            const int idx = it * 512 + t, si = idx >> 4, rq = idx & 15;
            preg[it] = make_float4(0.f, 0.f, 0.f, 0.f);
            if (si < nb)
                preg[it] = *(const float4*)&proj[(size_t)lidx[si] * RANK + rq * 4];
        }
        #pragma unroll
        for (int mt = 0; mt < 2; ++mt)
            #pragma unroll
            for (int reg = 0; reg < 4; ++reg) {
                const int si = wm * 32 + mt * 16 + quad * 4 + reg;
                const size_t rowb = (si < nb) ? ((size_t)lidx[si] * HIDDEN + hbase) : 0;
                #pragma unroll
                for (int nt = 0; nt < 4; ++nt) {
                    const int h = (wr * 4 + nt) * 16 + m16;
                    zep[mt][nt][reg] = (si < nb) ? z[rowb + h] : 0.f;
                }
            }
    }
    #pragma unroll
    for (int it = 0; it < 4; ++it) {
        const int idx = it * 512 + t, hh = idx >> 4, rq = idx & 15;
        *(ushort4*)&ut[hh * UPAD + rq * 4] = pack4(ureg[it]);
    }
    for (int p = 0; p < P; ++p) {
        const int nbr = n - p * MB_D;
        const int nb = (nbr < MB_D) ? nbr : MB_D;
        const int base = p * MB_D;
        #pragma unroll
        for (int it = 0; it < 4; ++it) {
            const int idx = it * 512 + t, si = idx >> 4, rq = idx & 15;
            *(ushort4*)&pt[p & 1][si * PPAD + rq * 4] = pack4(preg[it]);
        }
        __syncthreads();

        f32x4 acc[2][4];
        #pragma unroll
        for (int mt = 0; mt < 2; ++mt)
            #pragma unroll
            for (int nt = 0; nt < 4; ++nt)
                acc[mt][nt] = (f32x4){0.f, 0.f, 0.f, 0.f};

        const ushort* pr0 = &pt[p & 1][(wm * 32 + m16) * PPAD];
        const ushort* pr1 = pr0 + 16 * PPAD;
        #pragma unroll
        for (int kt = 0; kt < 2; ++kt) {
            const int koff = kt * 32 + quad * 8;
            const bf16x8 a0 = *(const bf16x8*)&pr0[koff];
            const bf16x8 a1 = *(const bf16x8*)&pr1[koff];
            #pragma unroll
            for (int nt = 0; nt < 4; ++nt) {
                const int h = (wr * 4 + nt) * 16 + m16;
                const bf16x8 bf = *(const bf16x8*)&ut[h * UPAD + koff];
                acc[0][nt] = __builtin_amdgcn_mfma_f32_16x16x32_bf16(a0, bf, acc[0][nt], 0, 0, 0);
                acc[1][nt] = __builtin_amdgcn_mfma_f32_16x16x32_bf16(a1, bf, acc[1][nt], 0, 0, 0);
            }
        }
        #pragma unroll
        for (int mt = 0; mt < 2; ++mt)
            #pragma unroll
            for (int reg = 0; reg < 4; ++reg) {
                const int si = wm * 32 + mt * 16 + quad * 4 + reg;
                if (si < nb) {
                    const size_t rowb = (size_t)lidx[base + si] * HIDDEN + hbase;
                    #pragma unroll
                    for (int nt = 0; nt < 4; ++nt) {
                        const int h = (wr * 4 + nt) * 16 + m16;
                        out[rowb + h] = zep[mt][nt][reg] + acc[mt][nt][reg];
                    }
                }
            }
        if (p + 1 < P) {
            const int b2 = (p + 1) * MB_D;
            const int nb2 = (n - b2 < MB_D) ? (n - b2) : MB_D;
            #pragma unroll
            for (int it = 0; it < 4; ++it) {
                const int idx = it * 512 + t, si = idx >> 4, rq = idx & 15;
                preg[it] = make_float4(0.f, 0.f, 0.f, 0.f);
                if (si < nb2)
                    preg[it] = *(const float4*)&proj[(size_t)lidx[b2 + si] * RANK + rq * 4];
            }
            #pragma unroll
            for (int mt = 0; mt < 2; ++mt)
                #pragma unroll
                for (int reg = 0; reg < 4; ++reg) {
                    const int si = wm * 32 + mt * 16 + quad * 4 + reg;
                    const size_t rowb = (si < nb2) ? ((size_t)lidx[b2 + si] * HIDDEN + hbase) : 0;
                    #pragma unroll
                    for (int nt = 0; nt < 4; ++nt) {
                        const int h = (wr * 4 + nt) * 16 + m16;
                        zep[mt][nt][reg] = (si < nb2) ? z[rowb + h] : 0.f;
                    }
                }
        }
    }
}

extern "C" void kernel_launch(void* const* d_in, const int* in_sizes, int n_in,
                              void* d_out, int out_size, void* d_ws, size_t ws_size,
                              hipStream_t stream)
{
    const float* z   = (const float*)d_in[0];
    const int*   ids = (const int*)d_in[1];
    const float* u   = (const float*)d_in[2];
    const float* v   = (const float*)d_in[3];
    float* out  = (float*)d_out;
    float* proj = (float*)d_ws;              // 512 KB, zeroed async below

    hipMemsetAsync(proj, 0, (size_t)BATCH * RANK * sizeof(float), stream);

    void* args[] = {(void*)&z, (void*)&v, (void*)&u, (void*)&ids,
                    (void*)&proj, (void*)&out};
    hipError_t rc = hipLaunchCooperativeKernel((void*)k_fused, dim3(256), dim3(512),
                                               args, 0, stream);
    if (rc != hipSuccess) {
        // fallback: known-good two-kernel path
        hipLaunchKernelGGL(k_proj_fb, dim3(HIDDEN / KC, NUM_LAYERS), dim3(512), 0,
                           stream, z, v, ids, proj);
        hipLaunchKernelGGL(k_delta_fb, dim3(HIDDEN / HCH, NUM_LAYERS), dim3(512), 0,
                           stream, z, u, ids, proj, out);
    }
}

// Round 4
// 110.144 us; speedup vs baseline: 1.4387x; 1.4387x over previous
//
#include <hip/hip_runtime.h>

#define NUM_LAYERS 32
#define HIDDEN 2048
#define RANK 64
#define BATCH 2048
#define KC 128               // h-chunk (K) per k_proj block
#define HCH 128              // h-chunk (N) per k_delta block
#define MB_P 64              // samples per pass, k_proj
#define MB_D 128             // samples per pass, k_delta
#define ZPAD 136             // ushort row stride, z tile (16B-aligned, 4-bank shift)
#define VPAD 136             // ushort row stride, v tile
#define UPAD 72              // ushort row stride, u tile
#define PPAD 72              // ushort row stride, p tile

typedef __attribute__((ext_vector_type(8))) short bf16x8;
typedef __attribute__((ext_vector_type(4))) float f32x4;

static __device__ __forceinline__ ushort f2bf(float x) {
    unsigned b = __builtin_bit_cast(unsigned, x);
    b += 0x7fffu + ((b >> 16) & 1u);          // round-to-nearest-even
    return (ushort)(b >> 16);
}
static __device__ __forceinline__ ushort4 pack4(float4 v) {
    ushort4 r; r.x = f2bf(v.x); r.y = f2bf(v.y); r.z = f2bf(v.z); r.w = f2bf(v.w);
    return r;
}

// K1: proj[b,r] += sum_{h in chunk} z[b,h] * v[l,h,r]   via MFMA bf16
// Self-derived sample list: each block scans ids (one int4/thread, L2-hot)
// and compacts matches into LDS. No bucket kernel, no perm buffer.
// 512 threads: wave w -> r-tile (w&3), sample-half (w>>2). 64 samples/pass.
__global__ __launch_bounds__(512)
void k_proj(const float* __restrict__ z, const float* __restrict__ v,
            const int* __restrict__ ids, float* __restrict__ proj)
{
    const int kc = blockIdx.x, l = blockIdx.y;
    const int t = threadIdx.x;
    const int w = t >> 6, lane = t & 63;
    const int m16 = lane & 15, quad = lane >> 4;
    const int wr = w & 3, wm = w >> 2;
    const int kbase = kc * KC;

    __shared__ int    lidx[BATCH];           // 8 KB (worst case all one layer)
    __shared__ int    nsh;
    __shared__ ushort vt[RANK * VPAD];       // 17 KB  [r][h] transposed
    __shared__ ushort zt[2][MB_P * ZPAD];    // 34 KB  [si][h] double-buffered

    if (t == 0) nsh = 0;

    // issue V loads first; they fly over the ids-scan/compaction
    float4 vreg[4];
    #pragma unroll
    for (int it = 0; it < 4; ++it) {
        const int idx = it * 512 + t;        // 2048 float4 = 128h x 16
        const int hh = idx >> 4, rq = idx & 15;
        vreg[it] = *(const float4*)&v[((size_t)l * HIDDEN + kbase + hh) * RANK + rq * 4];
    }
    __syncthreads();                         // nsh = 0 visible

    {
        const int4 iv = ((const int4*)ids)[t];   // 512 int4 = all 2048 ids
        if (iv.x == l) lidx[atomicAdd(&nsh, 1)] = t * 4 + 0;
        if (iv.y == l) lidx[atomicAdd(&nsh, 1)] = t * 4 + 1;
        if (iv.z == l) lidx[atomicAdd(&nsh, 1)] = t * 4 + 2;
        if (iv.w == l) lidx[atomicAdd(&nsh, 1)] = t * 4 + 3;
    }
    __syncthreads();                         // lidx, nsh final
    const int n = nsh;
    if (n == 0) return;

    const int P = (n + MB_P - 1) / MB_P;
    // issue pass-0 z gathers (overlap with V convert below)
    float4 zreg[4];
    {
        const int nb = (n < MB_P) ? n : MB_P;
        #pragma unroll
        for (int it = 0; it < 4; ++it) {
            const int idx = it * 512 + t;    // 2048 float4 = 64si x 32
            const int si = idx >> 5, q = idx & 31;
            zreg[it] = make_float4(0.f, 0.f, 0.f, 0.f);
            if (si < nb)
                zreg[it] = *(const float4*)&z[(size_t)lidx[si] * HIDDEN + kbase + q * 4];
        }
    }
    // convert + write V tile (transposed) while z loads fly
    #pragma unroll
    for (int it = 0; it < 4; ++it) {
        const int idx = it * 512 + t;
        const int hh = idx >> 4, rq = idx & 15;
        vt[(rq * 4 + 0) * VPAD + hh] = f2bf(vreg[it].x);
        vt[(rq * 4 + 1) * VPAD + hh] = f2bf(vreg[it].y);
        vt[(rq * 4 + 2) * VPAD + hh] = f2bf(vreg[it].z);
        vt[(rq * 4 + 3) * VPAD + hh] = f2bf(vreg[it].w);
    }

    for (int p = 0; p < P; ++p) {
        const int nbr = n - p * MB_P;
        const int nb = (nbr < MB_P) ? nbr : MB_P;
        #pragma unroll
        for (int it = 0; it < 4; ++it) {
            const int idx = it * 512 + t;
            const int si = idx >> 5, q = idx & 31;
            *(ushort4*)&zt[p & 1][si * ZPAD + q * 4] = pack4(zreg[it]);
        }
        __syncthreads();                     // vt (p==0) + zt[p&1] visible
        if (p + 1 < P) {                     // prefetch next pass into other buffer
            const int b2 = (p + 1) * MB_P;
            const int nb2r = n - b2;
            const int nb2 = (nb2r < MB_P) ? nb2r : MB_P;
            #pragma unroll
            for (int it = 0; it < 4; ++it) {
                const int idx = it * 512 + t;
                const int si = idx >> 5, q = idx & 31;
                zreg[it] = make_float4(0.f, 0.f, 0.f, 0.f);
                if (si < nb2)
                    zreg[it] = *(const float4*)&z[(size_t)lidx[b2 + si] * HIDDEN + kbase + q * 4];
            }
        }
        f32x4 acc0 = {0.f, 0.f, 0.f, 0.f}, acc1 = {0.f, 0.f, 0.f, 0.f};
        const ushort* zr0 = &zt[p & 1][(wm * 32 + m16) * ZPAD];
        const ushort* zr1 = zr0 + 16 * ZPAD;
        const ushort* vr  = &vt[(wr * 16 + m16) * VPAD];
        #pragma unroll
        for (int kt = 0; kt < 4; ++kt) {
            const int koff = kt * 32 + quad * 8;
            const bf16x8 bf = *(const bf16x8*)&vr[koff];
            const bf16x8 a0 = *(const bf16x8*)&zr0[koff];
            const bf16x8 a1 = *(const bf16x8*)&zr1[koff];
            acc0 = __builtin_amdgcn_mfma_f32_16x16x32_bf16(a0, bf, acc0, 0, 0, 0);
            acc1 = __builtin_amdgcn_mfma_f32_16x16x32_bf16(a1, bf, acc1, 0, 0, 0);
        }
        // C/D: col(=r)=lane&15, row(=si)=quad*4+reg ; fire-and-forget atomics
        const int r = wr * 16 + m16;
        const int base = p * MB_P;
        #pragma unroll
        for (int reg = 0; reg < 4; ++reg) {
            const int row = wm * 32 + quad * 4 + reg;
            if (row < nb)
                atomicAdd(&proj[(size_t)lidx[base + row] * RANK + r], acc0[reg]);
            if (row + 16 < nb)
                atomicAdd(&proj[(size_t)lidx[base + row + 16] * RANK + r], acc1[reg]);
        }
    }
}

// K2: out[b,h] = z[b,h] + sum_r proj[b,r] * u[l,h,r]   via MFMA bf16
// Same self-derived list. 512 threads: wave w -> h-tile (w&1, 64h),
// sample-group (w>>1, 32 samples). 128 samples/pass (P==1 almost always).
__global__ __launch_bounds__(512)
void k_delta(const float* __restrict__ z, const float* __restrict__ u,
             const int* __restrict__ ids, const float* __restrict__ proj,
             float* __restrict__ out)
{
    const int hc = blockIdx.x, l = blockIdx.y;
    const int t = threadIdx.x;
    const int w = t >> 6, lane = t & 63;
    const int m16 = lane & 15, quad = lane >> 4;
    const int wr = w & 1, wm = w >> 1;
    const int hbase = hc * HCH;

    __shared__ int    lidx[BATCH];           // 8 KB
    __shared__ int    nsh;
    __shared__ ushort ut[HCH * UPAD];        // 18 KB [h][r]
    __shared__ ushort pt[2][MB_D * PPAD];    // 36 KB [si][r] double-buffered

    if (t == 0) nsh = 0;

    // issue U loads first; they fly over the compaction
    float4 ureg[4];
    #pragma unroll
    for (int it = 0; it < 4; ++it) {
        const int idx = it * 512 + t;        // 2048 float4 = 128h x 16
        const int hh = idx >> 4, rq = idx & 15;
        ureg[it] = *(const float4*)&u[((size_t)l * HIDDEN + hbase + hh) * RANK + rq * 4];
    }
    __syncthreads();                         // nsh = 0 visible

    {
        const int4 iv = ((const int4*)ids)[t];
        if (iv.x == l) lidx[atomicAdd(&nsh, 1)] = t * 4 + 0;
        if (iv.y == l) lidx[atomicAdd(&nsh, 1)] = t * 4 + 1;
        if (iv.z == l) lidx[atomicAdd(&nsh, 1)] = t * 4 + 2;
        if (iv.w == l) lidx[atomicAdd(&nsh, 1)] = t * 4 + 3;
    }
    __syncthreads();                         // lidx, nsh final
    const int n = nsh;
    if (n == 0) return;

    const int P = (n + MB_D - 1) / MB_D;
    float4 preg[4];
    float  zep[2][4][4];
    {
        const int nb = (n < MB_D) ? n : MB_D;
        #pragma unroll
        for (int it = 0; it < 4; ++it) {     // 2048 float4 = 128si x 16
            const int idx = it * 512 + t;
            const int si = idx >> 4, rq = idx & 15;
            preg[it] = make_float4(0.f, 0.f, 0.f, 0.f);
            if (si < nb)
                preg[it] = *(const float4*)&proj[(size_t)lidx[si] * RANK + rq * 4];
        }
        #pragma unroll
        for (int mt = 0; mt < 2; ++mt)
            #pragma unroll
            for (int reg = 0; reg < 4; ++reg) {
                const int si = wm * 32 + mt * 16 + quad * 4 + reg;
                const size_t rowb = (si < nb) ? ((size_t)lidx[si] * HIDDEN + hbase) : 0;
                #pragma unroll
                for (int nt = 0; nt < 4; ++nt) {
                    const int h = (wr * 4 + nt) * 16 + m16;
                    zep[mt][nt][reg] = (si < nb) ? z[rowb + h] : 0.f;
                }
            }
    }
    // convert + write U tile while proj/z loads fly
    #pragma unroll
    for (int it = 0; it < 4; ++it) {
        const int idx = it * 512 + t;
        const int hh = idx >> 4, rq = idx & 15;
        *(ushort4*)&ut[hh * UPAD + rq * 4] = pack4(ureg[it]);
    }

    for (int p = 0; p < P; ++p) {
        const int nbr = n - p * MB_D;
        const int nb = (nbr < MB_D) ? nbr : MB_D;
        const int base = p * MB_D;
        #pragma unroll
        for (int it = 0; it < 4; ++it) {
            const int idx = it * 512 + t;
            const int si = idx >> 4, rq = idx & 15;
            *(ushort4*)&pt[p & 1][si * PPAD + rq * 4] = pack4(preg[it]);
        }
        __syncthreads();                     // ut (p==0) + pt[p&1] visible

        f32x4 acc[2][4];
        #pragma unroll
        for (int mt = 0; mt < 2; ++mt)
            #pragma unroll
            for (int nt = 0; nt < 4; ++nt)
                acc[mt][nt] = (f32x4){0.f, 0.f, 0.f, 0.f};

        const ushort* pr0 = &pt[p & 1][(wm * 32 + m16) * PPAD];
        const ushort* pr1 = pr0 + 16 * PPAD;
        #pragma unroll
        for (int kt = 0; kt < 2; ++kt) {
            const int koff = kt * 32 + quad * 8;
            const bf16x8 a0 = *(const bf16x8*)&pr0[koff];
            const bf16x8 a1 = *(const bf16x8*)&pr1[koff];
            #pragma unroll
            for (int nt = 0; nt < 4; ++nt) {
                const int h = (wr * 4 + nt) * 16 + m16;
                const bf16x8 bf = *(const bf16x8*)&ut[h * UPAD + koff];
                acc[0][nt] = __builtin_amdgcn_mfma_f32_16x16x32_bf16(a0, bf, acc[0][nt], 0, 0, 0);
                acc[1][nt] = __builtin_amdgcn_mfma_f32_16x16x32_bf16(a1, bf, acc[1][nt], 0, 0, 0);
            }
        }
        // epilogue: out = z + delta (z prefetched before the pass)
        #pragma unroll
        for (int mt = 0; mt < 2; ++mt)
            #pragma unroll
            for (int reg = 0; reg < 4; ++reg) {
                const int si = wm * 32 + mt * 16 + quad * 4 + reg;
                if (si < nb) {
                    const size_t rowb = (size_t)lidx[base + si] * HIDDEN + hbase;
                    #pragma unroll
                    for (int nt = 0; nt < 4; ++nt) {
                        const int h = (wr * 4 + nt) * 16 + m16;
                        out[rowb + h] = zep[mt][nt][reg] + acc[mt][nt][reg];
                    }
                }
            }
        // prefetch next pass (rare: only layers with n > 128)
        if (p + 1 < P) {
            const int b2 = (p + 1) * MB_D;
            const int nb2r = n - b2;
            const int nb2 = (nb2r < MB_D) ? nb2r : MB_D;
            #pragma unroll
            for (int it = 0; it < 4; ++it) {
                const int idx = it * 512 + t;
                const int si = idx >> 4, rq = idx & 15;
                preg[it] = make_float4(0.f, 0.f, 0.f, 0.f);
                if (si < nb2)
                    preg[it] = *(const float4*)&proj[(size_t)lidx[b2 + si] * RANK + rq * 4];
            }
            #pragma unroll
            for (int mt = 0; mt < 2; ++mt)
                #pragma unroll
                for (int reg = 0; reg < 4; ++reg) {
                    const int si = wm * 32 + mt * 16 + quad * 4 + reg;
                    const size_t rowb = (si < nb2) ? ((size_t)lidx[b2 + si] * HIDDEN + hbase) : 0;
                    #pragma unroll
                    for (int nt = 0; nt < 4; ++nt) {
                        const int h = (wr * 4 + nt) * 16 + m16;
                        zep[mt][nt][reg] = (si < nb2) ? z[rowb + h] : 0.f;
                    }
                }
        }
    }
}

extern "C" void kernel_launch(void* const* d_in, const int* in_sizes, int n_in,
                              void* d_out, int out_size, void* d_ws, size_t ws_size,
                              hipStream_t stream)
{
    const float* z   = (const float*)d_in[0];
    const int*   ids = (const int*)d_in[1];
    const float* u   = (const float*)d_in[2];
    const float* v   = (const float*)d_in[3];
    float* out = (float*)d_out;
    float* proj = (float*)d_ws;              // 512 KB, zeroed async below

    hipMemsetAsync(proj, 0, (size_t)BATCH * RANK * sizeof(float), stream);
    hipLaunchKernelGGL(k_proj, dim3(HIDDEN / KC, NUM_LAYERS), dim3(512), 0, stream,
                       z, v, ids, proj);
    hipLaunchKernelGGL(k_delta, dim3(HIDDEN / HCH, NUM_LAYERS), dim3(512), 0, stream,
                       z, u, ids, proj, out);
}